// Round 7
// baseline (1355.999 us; speedup 1.0000x reference)
//
#include <hip/hip_runtime.h>
#include <hip/hip_bf16.h>

#define KNN_K 20
typedef _Float16 f16;
typedef _Float16 half8 __attribute__((ext_vector_type(8)));
typedef float f32x4 __attribute__((ext_vector_type(4)));

__device__ __forceinline__ float lrelu(float x){ return x >= 0.f ? x : 0.2f*x; }
__device__ __forceinline__ f16 us2h(unsigned short u){ union{unsigned short u; f16 h;} x; x.u=u; return x.h; }
__device__ __forceinline__ unsigned short h2us(f16 h){ union{unsigned short u; f16 h;} x; x.h=h; return x.u; }

// u32 key: [31:16] order-mapped f16 distance (desc), [15:0] ~m (idx asc). Unique, always > 0.
__device__ __forceinline__ unsigned pack_key16(f16 v, int m){
  unsigned u = h2us(v);
  unsigned s = (u & 0x8000u) ? ((~u) & 0xFFFFu) : (u | 0x8000u);
  return (s << 16) | ((~(unsigned)m) & 0xFFFFu);
}

__device__ __forceinline__ void insert32(unsigned* tk, unsigned key){
  if (key > tk[KNN_K-1]){
    #pragma unroll
    for (int j = KNN_K-1; j >= 1; --j){
      unsigned pv = tk[j-1];
      bool keep = tk[j] > key;
      bool ins  = pv   > key;
      tk[j] = keep ? tk[j] : (ins ? key : pv);
    }
    if (tk[0] < key) tk[0] = key;
  }
}

__device__ __forceinline__ void merge_sorted(unsigned* tk, const unsigned* src){
  #pragma unroll
  for (int j=0;j<KNN_K;++j){
    unsigned key = src[j];
    if (key <= tk[KNN_K-1]) break;
    insert32(tk, key);
  }
}

// ---------------- build x0: CN f32 + padded f16 NC + xx ----------------
__global__ __launch_bounds__(256) void build_x0(
    const float* __restrict__ pos, const int* __restrict__ nt,
    float* __restrict__ x0CN, unsigned short* __restrict__ xh0,
    unsigned short* __restrict__ xx0, int N)
{
  int n = blockIdx.x*256 + threadIdx.x;
  if (n >= N) return;
  float v[12];
  v[0]=pos[n*3+0]; v[1]=pos[n*3+1]; v[2]=pos[n*3+2];
  int t = nt[n];
  #pragma unroll
  for (int c=0;c<9;++c) v[3+c] = (t==c) ? 1.f : 0.f;
  float xa = 0.f;
  #pragma unroll
  for (int c=0;c<12;++c){
    x0CN[(size_t)c*N+n] = v[c];
    f16 h = (f16)v[c];
    float hf = (float)h;
    xh0[(size_t)n*32+c] = h2us(h);
    f16 pe = (f16)(hf*hf);       // elementwise xh*xh rounds to f16
    xa += (float)pe;             // f32 accumulation (jax upcast semantics)
  }
  #pragma unroll
  for (int c=12;c<32;++c) xh0[(size_t)n*32+c] = 0;
  xx0[n] = h2us((f16)xa);
}

// ---------------- weight transpose: dst[c*O+o] = src[o*stride+coff+c] ----------------
__global__ __launch_bounds__(256) void transpose_w(
    const float* __restrict__ src, float* __restrict__ dst, int O, int C, int stride, int coff)
{
  int i = blockIdx.x*256 + threadIdx.x;
  if (i >= O*C) return;
  int o = i / C, c = i % C;
  dst[(size_t)c*O + o] = src[(size_t)o*stride + coff + c];
}

// ---------------- fused MFMA kNN: grid (N/16, 2 m-halves), 512 thr ----------------
// Two-level selection: shared 4-lane threshold tau (safe lower bound on the
// union's 20th-largest) + 4-deep deferred buffer; chain-inserts only on flush.
template<int C>
__global__ __launch_bounds__(512) void knn_mfma(
    const unsigned short* __restrict__ xh,  // [N][C] f16 bits
    const unsigned short* __restrict__ xx,  // [N]   f16 bits
    unsigned* __restrict__ pl,              // [2][N][20] partial sorted keys
    int N)
{
  __shared__ unsigned lists[32][17][KNN_K+1];  // padded: q-stride % 32 != 0
  int tid = threadIdx.x;
  int w = tid >> 6, lane = tid & 63;
  int g = lane >> 4, c = lane & 15;
  int n0 = blockIdx.x * 16;
  int ms = blockIdx.y;
  int htiles = (N >> 7);            // tiles of 64 in this half

  half8 bfrag[C/32];
  #pragma unroll
  for (int kc=0; kc<C/32; ++kc)
    bfrag[kc] = *reinterpret_cast<const half8*>(xh + (size_t)(n0 + c)*C + kc*32 + g*8);
  f16 qxx = us2h(xx[n0 + c]);

  unsigned tk[KNN_K];
  #pragma unroll
  for (int j=0;j<KNN_K;++j) tk[j] = 0u;
  unsigned b0=0u,b1=0u,b2=0u,b3=0u;
  int cnt = 0;
  unsigned tau = 0u;

  #define KNN_FLUSH() do { \
    if (cnt > 0) insert32(tk, b0); \
    if (cnt > 1) insert32(tk, b1); \
    if (cnt > 2) insert32(tk, b2); \
    if (cnt > 3) insert32(tk, b3); \
    cnt = 0; \
    unsigned thr_ = tk[KNN_K-1]; \
    thr_ = max(thr_, (unsigned)__shfl_xor((int)thr_, 16, 64)); \
    thr_ = max(thr_, (unsigned)__shfl_xor((int)thr_, 32, 64)); \
    tau = thr_; \
  } while(0)

  for (int t = w; t < htiles; t += 8){
    int mbase = ms*(N>>1) + (t << 6);
    #pragma unroll
    for (int msub=0; msub<4; ++msub){
      int mrow = mbase + msub*16;
      f32x4 acc = {0.f,0.f,0.f,0.f};
      #pragma unroll
      for (int kc=0; kc<C/32; ++kc){
        half8 af = *reinterpret_cast<const half8*>(xh + (size_t)(mrow + c)*C + kc*32 + g*8);
        acc = __builtin_amdgcn_mfma_f32_16x16x32_f16(af, bfrag[kc], acc, 0, 0, 0);
      }
      #pragma unroll
      for (int j=0;j<4;++j){
        int m = mrow + g*4 + j;
        f16 dh = (f16)acc[j];          // einsum output rounds to f16
        f16 mi = dh * (f16)(-2.0f);    // inner = -2*dot
        f16 xm = us2h(xx[m]);
        f16 t1 = (-xm) - mi;           // (-xx[m] - inner)
        f16 pdh = t1 - qxx;            // ... - xx[n]
        unsigned key = pack_key16(pdh, m);
        if (key > tau){ b3=b2; b2=b1; b1=b0; b0=key; ++cnt; }
        if (__any(cnt >= 4)) KNN_FLUSH();
      }
    }
  }
  KNN_FLUSH();
  #undef KNN_FLUSH

  {
    unsigned* dst = lists[w*4 + g][c];
    #pragma unroll
    for (int j=0;j<KNN_K;++j) dst[j] = tk[j];
  }
  __syncthreads();

  unsigned tk2[KNN_K];
  if (tid < 128){
    int n = tid >> 3, q = tid & 7;
    #pragma unroll
    for (int j=0;j<KNN_K;++j) tk2[j] = lists[q*4][n][j];
    for (int li=1; li<4; ++li) merge_sorted(tk2, lists[q*4 + li][n]);
  }
  __syncthreads();
  if (tid < 128){
    int n = tid >> 3, q = tid & 7;
    unsigned* dst = lists[q][n];
    #pragma unroll
    for (int j=0;j<KNN_K;++j) dst[j] = tk2[j];
  }
  __syncthreads();
  if (tid < 32){
    int n = tid >> 1, h = tid & 1;
    #pragma unroll
    for (int j=0;j<KNN_K;++j) tk2[j] = lists[h*4][n][j];
    for (int li=1; li<4; ++li) merge_sorted(tk2, lists[h*4 + li][n]);
  }
  __syncthreads();
  if (tid < 32){
    int n = tid >> 1, h = tid & 1;
    unsigned* dst = lists[h][n];
    #pragma unroll
    for (int j=0;j<KNN_K;++j) dst[j] = tk2[j];
  }
  __syncthreads();
  if (tid < 16){
    int n = tid;
    #pragma unroll
    for (int j=0;j<KNN_K;++j) tk2[j] = lists[0][n][j];
    merge_sorted(tk2, lists[1][n]);
    unsigned* dst = pl + ((size_t)ms*N + n0 + n)*KNN_K;
    #pragma unroll
    for (int j=0;j<KNN_K;++j) dst[j] = tk2[j];
  }
}

// merge the 2 m-half partials -> final idx
__global__ __launch_bounds__(256) void knn_final(
    const unsigned* __restrict__ pl, int* __restrict__ idx, int N)
{
  int n = blockIdx.x*256 + threadIdx.x;
  if (n >= N) return;
  unsigned tk[KNN_K];
  const unsigned* p0 = pl + (size_t)n*KNN_K;
  const unsigned* p1 = pl + ((size_t)N + n)*KNN_K;
  #pragma unroll
  for (int j=0;j<KNN_K;++j) tk[j] = p0[j];
  merge_sorted(tk, p1);
  #pragma unroll
  for (int j=0;j<KNN_K;++j)
    idx[(size_t)n*KNN_K + j] = (int)((~tk[j]) & 0xFFFFu);
}

// ---------------- per-point U/V precompute: Ut = t*(Wd X); Vtb = t*((Wc-Wd)X - m) + b ----------------
template<int CIN>
__global__ __launch_bounds__(256) void uv_kernel(
    const float* __restrict__ xCN, const float* __restrict__ W,  // [64][2*CIN]
    const float* __restrict__ bn,
    float* __restrict__ Ut, float* __restrict__ Vtb, int N)
{
  __shared__ float Ws[32][CIN];
  int tid = threadIdx.x;
  int mode = blockIdx.y;      // 0 = U (neighbor term), 1 = V (center term)
  int ob = blockIdx.z * 32;
  for (int i = tid; i < 32*CIN; i += 256){
    int oo = i / CIN, cc = i % CIN;
    float wd = W[(size_t)(ob+oo)*(2*CIN) + cc];
    float wc = W[(size_t)(ob+oo)*(2*CIN) + CIN + cc];
    Ws[oo][cc] = mode ? (wc - wd) : wd;
  }
  __syncthreads();
  int n = blockIdx.x*256 + tid;
  float x[CIN];
  #pragma unroll
  for (int c2=0;c2<CIN;++c2) x[c2] = xCN[(size_t)c2*N + n];
  float acc[32];
  #pragma unroll
  for (int oo=0;oo<32;++oo) acc[oo] = 0.f;
  #pragma unroll 4
  for (int c2=0;c2<CIN;++c2){
    float xv = x[c2];
    #pragma unroll
    for (int oo=0;oo<32;++oo) acc[oo] = fmaf(Ws[oo][c2], xv, acc[oo]);
  }
  float* dst = mode ? Vtb : Ut;
  #pragma unroll
  for (int oo=0;oo<32;++oo){
    int o = ob + oo;
    float t = bn[o] / sqrtf(bn[192+o] + 1e-5f);
    float val = mode ? fmaf(acc[oo] - bn[128+o], t, bn[64+o]) : acc[oo]*t;
    dst[(size_t)n*64 + o] = val;
  }
}

// ---------------- edge conv: e = lrelu(Ut[j]+Vtb[n]); opt f2 = lrelu(bn2(W2 e)); max over k ----------------
template<bool SECOND>
__global__ __launch_bounds__(256) void edge2(
    const float* __restrict__ Ut, const float* __restrict__ Vtb,
    const int* __restrict__ idx,
    const float* __restrict__ W2, const float* __restrict__ bn2,
    float* __restrict__ outCN, unsigned short* __restrict__ outh,
    unsigned short* __restrict__ outxx, int N)
{
  __shared__ float eb[2][4][64];
  int w = threadIdx.x >> 6, o = threadIdx.x & 63;
  float w2r[64]; float t2=0.f,b2=0.f,m2=0.f;
  if (SECOND){
    #pragma unroll
    for (int c4=0;c4<16;++c4){
      float4 wv = *reinterpret_cast<const float4*>(W2 + (size_t)o*64 + c4*4);
      w2r[c4*4+0]=wv.x; w2r[c4*4+1]=wv.y; w2r[c4*4+2]=wv.z; w2r[c4*4+3]=wv.w;
    }
    t2 = bn2[o]/sqrtf(bn2[192+o]+1e-5f); b2 = bn2[64+o]; m2 = bn2[128+o];
  }
  #pragma unroll 1
  for (int q=0;q<2;++q){
    int n = blockIdx.x*8 + w*2 + q;
    float vo = Vtb[(size_t)n*64 + o];
    float best = -INFINITY;
    #pragma unroll 1
    for (int k=0;k<KNN_K;++k){
      int j = idx[(size_t)n*KNN_K + k];
      float e = lrelu(Ut[(size_t)j*64 + o] + vo);
      if (SECOND){
        eb[k&1][w][o] = e;
        __syncthreads();
        const float* ep = eb[k&1][w];
        float s0=0.f,s1=0.f,s2=0.f,s3=0.f;
        #pragma unroll
        for (int c4=0;c4<16;++c4){
          float4 ev = *reinterpret_cast<const float4*>(ep + c4*4);
          s0 = fmaf(w2r[c4*4+0], ev.x, s0);
          s1 = fmaf(w2r[c4*4+1], ev.y, s1);
          s2 = fmaf(w2r[c4*4+2], ev.z, s2);
          s3 = fmaf(w2r[c4*4+3], ev.w, s3);
        }
        float s = (s0+s1)+(s2+s3);
        float f = lrelu(fmaf(s - m2, t2, b2));
        best = fmaxf(best, f);
      } else {
        best = fmaxf(best, e);
      }
    }
    outCN[(size_t)o*N + n] = best;
    if (SECOND){
      f16 h = (f16)best; float hf = (float)h;
      outh[(size_t)n*64 + o] = h2us(h);
      float pe = (float)(f16)(hf*hf);
      float ssum = pe;
      #pragma unroll
      for (int s2s=32;s2s>=1;s2s>>=1) ssum += __shfl_xor(ssum, s2s, 64);
      if (o == 0) outxx[n] = h2us((f16)ssum);
    }
  }
}

// ---------------- fused 1x1-conv v3: o-tile 64 x n-tile 128, LDS-staged weights ----------------
template<bool DOMAX>
__global__ __launch_bounds__(256) void conv_fused(
    const float* __restrict__ WT, int O,
    const float* __restrict__ sA, int cAn,
    const float* __restrict__ sB, int cBn,
    const float* __restrict__ sC, int cCn,
    const float* __restrict__ bnp,
    const float* __restrict__ extra,
    float* __restrict__ out, int N)
{
  __shared__ float ws[32][68];
  int tid = threadIdx.x;
  int ln = tid & 63;
  int og = (tid >> 6) * 16;          // wave-uniform o sub-offset
  int n0 = blockIdx.x*128;
  int ob = blockIdx.y*64;
  int n = n0 + ln*2;
  float a0[16], a1[16];
  #pragma unroll
  for (int i=0;i<16;++i){ a0[i]=0.f; a1[i]=0.f; }

  const float* srcs[3] = {sA, sB, sC};
  int cnts[3] = {cAn, cBn, cCn};
  int cbase = 0;
  #pragma unroll 1
  for (int sidx=0; sidx<3; ++sidx){
    const float* s = srcs[sidx];
    if (!s) continue;
    int cn = cnts[sidx];
    #pragma unroll 1
    for (int c0=0; c0<cn; c0+=32){
      __syncthreads();
      #pragma unroll
      for (int r=0;r<8;++r){
        int i = r*256 + tid;
        int cc = i >> 6, oo = i & 63;
        ws[cc][oo] = WT[(size_t)(cbase+c0+cc)*O + ob + oo];
      }
      __syncthreads();
      #pragma unroll 4
      for (int cc=0; cc<32; ++cc){
        float2 xv = *reinterpret_cast<const float2*>(s + (size_t)(c0+cc)*N + n);
        const float* wr = &ws[cc][og];
        #pragma unroll
        for (int i=0;i<16;++i){
          a0[i] = fmaf(wr[i], xv.x, a0[i]);
          a1[i] = fmaf(wr[i], xv.y, a1[i]);
        }
      }
    }
    cbase += cn;
  }
  #pragma unroll
  for (int i=0;i<16;++i){
    int oG = ob + og + i;
    float t = bnp[oG] / sqrtf(bnp[3*O+oG] + 1e-5f);
    float e = extra ? extra[oG] : 0.f;
    float mm = bnp[2*O+oG], bb = bnp[1*O+oG];
    a0[i] = lrelu(fmaf((a0[i]+e) - mm, t, bb));
    a1[i] = lrelu(fmaf((a1[i]+e) - mm, t, bb));
  }
  if (!DOMAX){
    #pragma unroll
    for (int i=0;i<16;++i){
      float2 st = {a0[i], a1[i]};
      *reinterpret_cast<float2*>(out + (size_t)(ob+og+i)*N + n) = st;
    }
  } else {
    #pragma unroll
    for (int i=0;i<16;++i){
      float v = fmaxf(a0[i], a1[i]);
      #pragma unroll
      for (int s=32;s>=1;s>>=1) v = fmaxf(v, __shfl_xor(v, s, 64));
      if (ln == 0) out[(size_t)(ob+og+i)*gridDim.x + blockIdx.x] = v;
    }
  }
}

__global__ __launch_bounds__(256) void gmax_final(
    const float* __restrict__ gpart, float* __restrict__ g, int O, int P)
{
  int o = blockIdx.x*256 + threadIdx.x;
  if (o >= O) return;
  float m = -INFINITY;
  for (int p=0;p<P;++p) m = fmaxf(m, gpart[(size_t)o*P + p]);
  g[o] = m;
}

// lane-parallel over c with shuffle reduce; one o per wave
__global__ __launch_bounds__(256) void bias7_kernel(
    const float* __restrict__ W7, const float* __restrict__ g, float* __restrict__ b7)
{
  int w = threadIdx.x >> 6, ln = threadIdx.x & 63;
  int o = blockIdx.x*4 + w;
  if (o >= 512) return;
  float a = 0.f;
  #pragma unroll
  for (int c0=0; c0<1024; c0+=64)
    a = fmaf(W7[(size_t)o*1216 + c0 + ln], g[c0 + ln], a);
  #pragma unroll
  for (int s=32;s>=1;s>>=1) a += __shfl_xor(a, s, 64);
  if (ln == 0) b7[o] = a;
}

__global__ __launch_bounds__(256) void w9_kernel(
    const float* __restrict__ W9, const float* __restrict__ h8, float* __restrict__ out, int N)
{
  int n = blockIdx.x*256 + threadIdx.x;
  if (n >= N) return;
  float a0=0.f, a1=0.f, a2=0.f;
  for (int c=0;c<256;++c){
    float xv = h8[(size_t)c*N + n];
    a0 = fmaf(W9[c],       xv, a0);
    a1 = fmaf(W9[256+c],   xv, a1);
    a2 = fmaf(W9[512+c],   xv, a2);
  }
  out[(size_t)n*3+0]=a0; out[(size_t)n*3+1]=a1; out[(size_t)n*3+2]=a2;
}

extern "C" void kernel_launch(void* const* d_in, const int* in_sizes, int n_in,
                              void* d_out, int out_size, void* d_ws, size_t ws_size,
                              hipStream_t stream) {
  const float* curr_pos = (const float*)d_in[0];
  const int*   node_t   = (const int*)  d_in[1];
  const float* W1 = (const float*)d_in[2];
  const float* W2 = (const float*)d_in[3];
  const float* W3 = (const float*)d_in[4];
  const float* W4 = (const float*)d_in[5];
  const float* W5 = (const float*)d_in[6];
  const float* W6 = (const float*)d_in[7];
  const float* W7 = (const float*)d_in[8];
  const float* W8 = (const float*)d_in[9];
  const float* W9 = (const float*)d_in[10];
  const float* bn1 = (const float*)d_in[11];
  const float* bn2 = (const float*)d_in[12];
  const float* bn3 = (const float*)d_in[13];
  const float* bn4 = (const float*)d_in[14];
  const float* bn5 = (const float*)d_in[15];
  const float* bn6 = (const float*)d_in[16];
  const float* bn7 = (const float*)d_in[17];
  const float* bn8 = (const float*)d_in[18];
  float* out = (float*)d_out;

  const int N = in_sizes[0] / 3;

  char* ws = (char*)d_ws;
  size_t off = 0;
  auto A = [&](size_t b){ size_t o = off; off = (o + b + 255) & ~(size_t)255; return o; };

  float* x0CN = (float*)(ws + A((size_t)N*12*4));
  unsigned short* xh0 = (unsigned short*)(ws + A((size_t)N*32*2));
  unsigned short* xx0 = (unsigned short*)(ws + A((size_t)N*2));
  float* x1CN = (float*)(ws + A((size_t)N*64*4));
  unsigned short* xh1 = (unsigned short*)(ws + A((size_t)N*64*2));
  unsigned short* xx1 = (unsigned short*)(ws + A((size_t)N*2));
  float* x2CN = (float*)(ws + A((size_t)N*64*4));
  unsigned short* xh2 = (unsigned short*)(ws + A((size_t)N*64*2));
  unsigned short* xx2 = (unsigned short*)(ws + A((size_t)N*2));
  float* x3CN = (float*)(ws + A((size_t)N*64*4));
  int* idxb = (int*)(ws + A((size_t)N*KNN_K*4));
  unsigned* pl = (unsigned*)(ws + A((size_t)2*N*KNN_K*4));
  float* Ut  = (float*)(ws + A((size_t)N*64*4));
  float* Vtb = (float*)(ws + A((size_t)N*64*4));
  float* w6t  = (float*)(ws + A((size_t)192*1024*4));
  float* w7xt = (float*)(ws + A((size_t)192*512*4));
  float* w8t  = (float*)(ws + A((size_t)512*256*4));
  float* gpart= (float*)(ws + A((size_t)1024*(N/64)*4));
  float* gbuf = (float*)(ws + A((size_t)1024*4));
  float* b7   = (float*)(ws + A((size_t)512*4));

  size_t h7B   = (size_t)512*N*4;
  size_t h8B   = (size_t)256*N*4;
  size_t uniOff = A(((h7B + 255) & ~(size_t)255) + h8B);
  float* h7   = (float*)(ws + uniOff);
  float* h8   = (float*)(ws + uniOff + ((h7B + 255) & ~(size_t)255));
  if (off > ws_size) return;

  dim3 b256(256), b512(512);
  build_x0<<<dim3((N+255)/256), b256, 0, stream>>>(curr_pos, node_t, x0CN, xh0, xx0, N);
  transpose_w<<<dim3((1024*192+255)/256), b256, 0, stream>>>(W6, w6t, 1024, 192, 192, 0);
  transpose_w<<<dim3((512*192+255)/256),  b256, 0, stream>>>(W7, w7xt, 512, 192, 1216, 1024);
  transpose_w<<<dim3((256*512+255)/256),  b256, 0, stream>>>(W8, w8t, 256, 512, 512, 0);

  dim3 gknn(N/16, 2);
  dim3 guv(N/256, 2, 2);
  dim3 gec(N/8);
  dim3 gfin((N+255)/256);

  // round 1
  knn_mfma<32><<<gknn, b512, 0, stream>>>(xh0, xx0, pl, N);
  knn_final<<<gfin, b256, 0, stream>>>(pl, idxb, N);
  uv_kernel<12><<<guv, b256, 0, stream>>>(x0CN, W1, bn1, Ut, Vtb, N);
  edge2<true><<<gec, b256, 0, stream>>>(Ut, Vtb, idxb, W2, bn2, x1CN, xh1, xx1, N);
  // round 2
  knn_mfma<64><<<gknn, b512, 0, stream>>>(xh1, xx1, pl, N);
  knn_final<<<gfin, b256, 0, stream>>>(pl, idxb, N);
  uv_kernel<64><<<guv, b256, 0, stream>>>(x1CN, W3, bn3, Ut, Vtb, N);
  edge2<true><<<gec, b256, 0, stream>>>(Ut, Vtb, idxb, W4, bn4, x2CN, xh2, xx2, N);
  // round 3
  knn_mfma<64><<<gknn, b512, 0, stream>>>(xh2, xx2, pl, N);
  knn_final<<<gfin, b256, 0, stream>>>(pl, idxb, N);
  uv_kernel<64><<<guv, b256, 0, stream>>>(x2CN, W5, bn5, Ut, Vtb, N);
  edge2<false><<<gec, b256, 0, stream>>>(Ut, Vtb, idxb, nullptr, nullptr, x3CN, nullptr, nullptr, N);
  // head
  conv_fused<true><<<dim3(N/128, 16), b256, 0, stream>>>(w6t, 1024, x1CN, 64, x2CN, 64, x3CN, 64, bn6, nullptr, gpart, N);
  gmax_final<<<dim3(4), b256, 0, stream>>>(gpart, gbuf, 1024, N/128);
  bias7_kernel<<<dim3(128), b256, 0, stream>>>(W7, gbuf, b7);
  conv_fused<false><<<dim3(N/128, 8), b256, 0, stream>>>(w7xt, 512, x1CN, 64, x2CN, 64, x3CN, 64, bn7, b7, h7, N);
  conv_fused<false><<<dim3(N/128, 4), b256, 0, stream>>>(w8t, 256, h7, 512, nullptr, 0, nullptr, 0, bn8, nullptr, h8, N);
  w9_kernel<<<gfin, b256, 0, stream>>>(W9, h8, out, N);
}

// Round 8
// 1017.802 us; speedup vs baseline: 1.3323x; 1.3323x over previous
//
#include <hip/hip_runtime.h>
#include <hip/hip_bf16.h>

#define KNN_K 20
typedef _Float16 f16;
typedef _Float16 half8 __attribute__((ext_vector_type(8)));
typedef float f32x4 __attribute__((ext_vector_type(4)));

__device__ __forceinline__ float lrelu(float x){ return x >= 0.f ? x : 0.2f*x; }
__device__ __forceinline__ f16 us2h(unsigned short u){ union{unsigned short u; f16 h;} x; x.u=u; return x.h; }
__device__ __forceinline__ unsigned short h2us(f16 h){ union{unsigned short u; f16 h;} x; x.h=h; return x.u; }

// u32 key: [31:16] order-mapped f16 distance (desc), [15:0] ~m (idx asc). Unique, always > 0.
__device__ __forceinline__ unsigned pack_key16(f16 v, int m){
  unsigned u = h2us(v);
  unsigned s = (u & 0x8000u) ? ((~u) & 0xFFFFu) : (u | 0x8000u);
  return (s << 16) | ((~(unsigned)m) & 0xFFFFu);
}

// sorted-desc insert via min/max carry chain: 2 VALU/slot, branchless body.
__device__ __forceinline__ void insert32(unsigned* tk, unsigned key){
  if (key > tk[KNN_K-1]){
    unsigned c = key;
    #pragma unroll
    for (int j=0;j<KNN_K;++j){
      unsigned hi = max(tk[j], c);
      unsigned lo = min(tk[j], c);
      tk[j] = hi;
      c = lo;
    }
  }
}

__device__ __forceinline__ void merge_sorted(unsigned* tk, const unsigned* src){
  #pragma unroll
  for (int j=0;j<KNN_K;++j){
    unsigned key = src[j];
    if (key <= tk[KNN_K-1]) break;
    insert32(tk, key);
  }
}

// ---------------- build x0: CN f32 + padded f16 NC + xx ----------------
__global__ __launch_bounds__(256) void build_x0(
    const float* __restrict__ pos, const int* __restrict__ nt,
    float* __restrict__ x0CN, unsigned short* __restrict__ xh0,
    unsigned short* __restrict__ xx0, int N)
{
  int n = blockIdx.x*256 + threadIdx.x;
  if (n >= N) return;
  float v[12];
  v[0]=pos[n*3+0]; v[1]=pos[n*3+1]; v[2]=pos[n*3+2];
  int t = nt[n];
  #pragma unroll
  for (int c=0;c<9;++c) v[3+c] = (t==c) ? 1.f : 0.f;
  float xa = 0.f;
  #pragma unroll
  for (int c=0;c<12;++c){
    x0CN[(size_t)c*N+n] = v[c];
    f16 h = (f16)v[c];
    float hf = (float)h;
    xh0[(size_t)n*32+c] = h2us(h);
    f16 pe = (f16)(hf*hf);       // elementwise xh*xh rounds to f16
    xa += (float)pe;             // f32 accumulation (jax upcast semantics)
  }
  #pragma unroll
  for (int c=12;c<32;++c) xh0[(size_t)n*32+c] = 0;
  xx0[n] = h2us((f16)xa);
}

// ---------------- weight transpose: dst[c*O+o] = src[o*stride+coff+c] ----------------
__global__ __launch_bounds__(256) void transpose_w(
    const float* __restrict__ src, float* __restrict__ dst, int O, int C, int stride, int coff)
{
  int i = blockIdx.x*256 + threadIdx.x;
  if (i >= O*C) return;
  int o = i / C, c = i % C;
  dst[(size_t)c*O + o] = src[(size_t)o*stride + coff + c];
}

// ---------------- fused MFMA kNN: grid (N/16, 2 m-halves), 512 thr ----------------
template<int C>
__global__ __launch_bounds__(512) void knn_mfma(
    const unsigned short* __restrict__ xh,  // [N][C] f16 bits
    const unsigned short* __restrict__ xx,  // [N]   f16 bits
    unsigned* __restrict__ pl,              // [2][N][20] partial sorted keys
    int N)
{
  __shared__ unsigned lists[32][17][KNN_K+1];  // padded: conflict-light
  int tid = threadIdx.x;
  int w = tid >> 6, lane = tid & 63;
  int g = lane >> 4, c = lane & 15;
  int n0 = blockIdx.x * 16;
  int ms = blockIdx.y;
  int htiles = (N >> 7);            // tiles of 64 in this half

  half8 bfrag[C/32];
  #pragma unroll
  for (int kc=0; kc<C/32; ++kc)
    bfrag[kc] = *reinterpret_cast<const half8*>(xh + (size_t)(n0 + c)*C + kc*32 + g*8);
  f16 qxx = us2h(xx[n0 + c]);

  unsigned tk[KNN_K];
  #pragma unroll
  for (int j=0;j<KNN_K;++j) tk[j] = 0u;

  for (int t = w; t < htiles; t += 8){
    int mbase = ms*(N>>1) + (t << 6);
    #pragma unroll
    for (int msub=0; msub<4; ++msub){
      int mrow = mbase + msub*16;
      f32x4 acc = {0.f,0.f,0.f,0.f};
      #pragma unroll
      for (int kc=0; kc<C/32; ++kc){
        half8 af = *reinterpret_cast<const half8*>(xh + (size_t)(mrow + c)*C + kc*32 + g*8);
        acc = __builtin_amdgcn_mfma_f32_16x16x32_f16(af, bfrag[kc], acc, 0, 0, 0);
      }
      #pragma unroll
      for (int j=0;j<4;++j){
        int m = mrow + g*4 + j;
        f16 dh = (f16)acc[j];          // einsum output rounds to f16
        f16 mi = dh * (f16)(-2.0f);    // inner = -2*dot
        f16 xm = us2h(xx[m]);
        f16 t1 = (-xm) - mi;           // (-xx[m] - inner)
        f16 pdh = t1 - qxx;            // ... - xx[n]
        insert32(tk, pack_key16(pdh, m));
      }
    }
  }

  {
    unsigned* dst = lists[w*4 + g][c];
    #pragma unroll
    for (int j=0;j<KNN_K;++j) dst[j] = tk[j];
  }
  __syncthreads();

  unsigned tk2[KNN_K];
  if (tid < 128){
    int n = tid >> 3, q = tid & 7;
    #pragma unroll
    for (int j=0;j<KNN_K;++j) tk2[j] = lists[q*4][n][j];
    for (int li=1; li<4; ++li) merge_sorted(tk2, lists[q*4 + li][n]);
  }
  __syncthreads();
  if (tid < 128){
    int n = tid >> 3, q = tid & 7;
    unsigned* dst = lists[q][n];
    #pragma unroll
    for (int j=0;j<KNN_K;++j) dst[j] = tk2[j];
  }
  __syncthreads();
  if (tid < 32){
    int n = tid >> 1, h = tid & 1;
    #pragma unroll
    for (int j=0;j<KNN_K;++j) tk2[j] = lists[h*4][n][j];
    for (int li=1; li<4; ++li) merge_sorted(tk2, lists[h*4 + li][n]);
  }
  __syncthreads();
  if (tid < 32){
    int n = tid >> 1, h = tid & 1;
    unsigned* dst = lists[h][n];
    #pragma unroll
    for (int j=0;j<KNN_K;++j) dst[j] = tk2[j];
  }
  __syncthreads();
  if (tid < 16){
    int n = tid;
    #pragma unroll
    for (int j=0;j<KNN_K;++j) tk2[j] = lists[0][n][j];
    merge_sorted(tk2, lists[1][n]);
    unsigned* dst = pl + ((size_t)ms*N + n0 + n)*KNN_K;
    #pragma unroll
    for (int j=0;j<KNN_K;++j) dst[j] = tk2[j];
  }
}

// merge the 2 m-half partials -> final idx
__global__ __launch_bounds__(256) void knn_final(
    const unsigned* __restrict__ pl, int* __restrict__ idx, int N)
{
  int n = blockIdx.x*256 + threadIdx.x;
  if (n >= N) return;
  unsigned tk[KNN_K];
  const unsigned* p0 = pl + (size_t)n*KNN_K;
  const unsigned* p1 = pl + ((size_t)N + n)*KNN_K;
  #pragma unroll
  for (int j=0;j<KNN_K;++j) tk[j] = p0[j];
  merge_sorted(tk, p1);
  #pragma unroll
  for (int j=0;j<KNN_K;++j)
    idx[(size_t)n*KNN_K + j] = (int)((~tk[j]) & 0xFFFFu);
}

// ---------------- per-point U/V precompute: Ut = t*(Wd X); Vtb = t*((Wc-Wd)X - m) + b ----------------
template<int CIN>
__global__ __launch_bounds__(256) void uv_kernel(
    const float* __restrict__ xCN, const float* __restrict__ W,  // [64][2*CIN]
    const float* __restrict__ bn,
    float* __restrict__ Ut, float* __restrict__ Vtb, int N)
{
  __shared__ float Ws[32][CIN];
  int tid = threadIdx.x;
  int mode = blockIdx.y;      // 0 = U (neighbor term), 1 = V (center term)
  int ob = blockIdx.z * 32;
  for (int i = tid; i < 32*CIN; i += 256){
    int oo = i / CIN, cc = i % CIN;
    float wd = W[(size_t)(ob+oo)*(2*CIN) + cc];
    float wc = W[(size_t)(ob+oo)*(2*CIN) + CIN + cc];
    Ws[oo][cc] = mode ? (wc - wd) : wd;
  }
  __syncthreads();
  int n = blockIdx.x*256 + tid;
  float x[CIN];
  #pragma unroll
  for (int c2=0;c2<CIN;++c2) x[c2] = xCN[(size_t)c2*N + n];
  float acc[32];
  #pragma unroll
  for (int oo=0;oo<32;++oo) acc[oo] = 0.f;
  #pragma unroll 4
  for (int c2=0;c2<CIN;++c2){
    float xv = x[c2];
    #pragma unroll
    for (int oo=0;oo<32;++oo) acc[oo] = fmaf(Ws[oo][c2], xv, acc[oo]);
  }
  float* dst = mode ? Vtb : Ut;
  #pragma unroll
  for (int oo=0;oo<32;++oo){
    int o = ob + oo;
    float t = bn[o] / sqrtf(bn[192+o] + 1e-5f);
    float val = mode ? fmaf(acc[oo] - bn[128+o], t, bn[64+o]) : acc[oo]*t;
    dst[(size_t)n*64 + o] = val;
  }
}

// ---------------- edge conv: e = lrelu(Ut[j]+Vtb[n]); opt f2 = lrelu(bn2(W2 e)); max over k ----------------
// Per-wave LDS broadcast; no barriers needed (each wave reads only its own slice;
// per-wave DS ops execute in order).
template<bool SECOND>
__global__ __launch_bounds__(256) void edge2(
    const float* __restrict__ Ut, const float* __restrict__ Vtb,
    const int* __restrict__ idx,
    const float* __restrict__ W2, const float* __restrict__ bn2,
    float* __restrict__ outCN, unsigned short* __restrict__ outh,
    unsigned short* __restrict__ outxx, int N)
{
  __shared__ float eb[2][4][64];
  int w = threadIdx.x >> 6, o = threadIdx.x & 63;
  float w2r[64]; float t2=0.f,b2=0.f,m2=0.f;
  if (SECOND){
    #pragma unroll
    for (int c4=0;c4<16;++c4){
      float4 wv = *reinterpret_cast<const float4*>(W2 + (size_t)o*64 + c4*4);
      w2r[c4*4+0]=wv.x; w2r[c4*4+1]=wv.y; w2r[c4*4+2]=wv.z; w2r[c4*4+3]=wv.w;
    }
    t2 = bn2[o]/sqrtf(bn2[192+o]+1e-5f); b2 = bn2[64+o]; m2 = bn2[128+o];
  }
  #pragma unroll 1
  for (int q=0;q<2;++q){
    int n = blockIdx.x*8 + w*2 + q;
    float vo = Vtb[(size_t)n*64 + o];
    float best = -INFINITY;
    #pragma unroll 1
    for (int k=0;k<KNN_K;++k){
      int j = idx[(size_t)n*KNN_K + k];
      float e = lrelu(Ut[(size_t)j*64 + o] + vo);
      if (SECOND){
        eb[k&1][w][o] = e;
        const float* ep = eb[k&1][w];
        float s0=0.f,s1=0.f,s2=0.f,s3=0.f;
        #pragma unroll
        for (int c4=0;c4<16;++c4){
          float4 ev = *reinterpret_cast<const float4*>(ep + c4*4);
          s0 = fmaf(w2r[c4*4+0], ev.x, s0);
          s1 = fmaf(w2r[c4*4+1], ev.y, s1);
          s2 = fmaf(w2r[c4*4+2], ev.z, s2);
          s3 = fmaf(w2r[c4*4+3], ev.w, s3);
        }
        float s = (s0+s1)+(s2+s3);
        float f = lrelu(fmaf(s - m2, t2, b2));
        best = fmaxf(best, f);
      } else {
        best = fmaxf(best, e);
      }
    }
    outCN[(size_t)o*N + n] = best;
    if (SECOND){
      f16 h = (f16)best; float hf = (float)h;
      outh[(size_t)n*64 + o] = h2us(h);
      float pe = (float)(f16)(hf*hf);
      float ssum = pe;
      #pragma unroll
      for (int s2s=32;s2s>=1;s2s>>=1) ssum += __shfl_xor(ssum, s2s, 64);
      if (o == 0) outxx[n] = h2us((f16)ssum);
    }
  }
}

// ---------------- fused 1x1-conv v3: o-tile 64 x n-tile 128, LDS-staged weights ----------------
template<bool DOMAX>
__global__ __launch_bounds__(256) void conv_fused(
    const float* __restrict__ WT, int O,
    const float* __restrict__ sA, int cAn,
    const float* __restrict__ sB, int cBn,
    const float* __restrict__ sC, int cCn,
    const float* __restrict__ bnp,
    const float* __restrict__ extra,
    float* __restrict__ out, int N)
{
  __shared__ float ws[32][68];
  int tid = threadIdx.x;
  int ln = tid & 63;
  int og = (tid >> 6) * 16;          // wave-uniform o sub-offset
  int n0 = blockIdx.x*128;
  int ob = blockIdx.y*64;
  int n = n0 + ln*2;
  float a0[16], a1[16];
  #pragma unroll
  for (int i=0;i<16;++i){ a0[i]=0.f; a1[i]=0.f; }

  const float* srcs[3] = {sA, sB, sC};
  int cnts[3] = {cAn, cBn, cCn};
  int cbase = 0;
  #pragma unroll 1
  for (int sidx=0; sidx<3; ++sidx){
    const float* s = srcs[sidx];
    if (!s) continue;
    int cn = cnts[sidx];
    #pragma unroll 1
    for (int c0=0; c0<cn; c0+=32){
      __syncthreads();
      #pragma unroll
      for (int r=0;r<8;++r){
        int i = r*256 + tid;
        int cc = i >> 6, oo = i & 63;
        ws[cc][oo] = WT[(size_t)(cbase+c0+cc)*O + ob + oo];
      }
      __syncthreads();
      #pragma unroll 4
      for (int cc=0; cc<32; ++cc){
        float2 xv = *reinterpret_cast<const float2*>(s + (size_t)(c0+cc)*N + n);
        const float* wr = &ws[cc][og];
        #pragma unroll
        for (int i=0;i<16;++i){
          a0[i] = fmaf(wr[i], xv.x, a0[i]);
          a1[i] = fmaf(wr[i], xv.y, a1[i]);
        }
      }
    }
    cbase += cn;
  }
  #pragma unroll
  for (int i=0;i<16;++i){
    int oG = ob + og + i;
    float t = bnp[oG] / sqrtf(bnp[3*O+oG] + 1e-5f);
    float e = extra ? extra[oG] : 0.f;
    float mm = bnp[2*O+oG], bb = bnp[1*O+oG];
    a0[i] = lrelu(fmaf((a0[i]+e) - mm, t, bb));
    a1[i] = lrelu(fmaf((a1[i]+e) - mm, t, bb));
  }
  if (!DOMAX){
    #pragma unroll
    for (int i=0;i<16;++i){
      float2 st = {a0[i], a1[i]};
      *reinterpret_cast<float2*>(out + (size_t)(ob+og+i)*N + n) = st;
    }
  } else {
    #pragma unroll
    for (int i=0;i<16;++i){
      float v = fmaxf(a0[i], a1[i]);
      #pragma unroll
      for (int s=32;s>=1;s>>=1) v = fmaxf(v, __shfl_xor(v, s, 64));
      if (ln == 0) out[(size_t)(ob+og+i)*gridDim.x + blockIdx.x] = v;
    }
  }
}

__global__ __launch_bounds__(256) void gmax_final(
    const float* __restrict__ gpart, float* __restrict__ g, int O, int P)
{
  int o = blockIdx.x*256 + threadIdx.x;
  if (o >= O) return;
  float m = -INFINITY;
  for (int p=0;p<P;++p) m = fmaxf(m, gpart[(size_t)o*P + p]);
  g[o] = m;
}

// lane-parallel over c with shuffle reduce; one o per wave
__global__ __launch_bounds__(256) void bias7_kernel(
    const float* __restrict__ W7, const float* __restrict__ g, float* __restrict__ b7)
{
  int w = threadIdx.x >> 6, ln = threadIdx.x & 63;
  int o = blockIdx.x*4 + w;
  if (o >= 512) return;
  float a = 0.f;
  #pragma unroll
  for (int c0=0; c0<1024; c0+=64)
    a = fmaf(W7[(size_t)o*1216 + c0 + ln], g[c0 + ln], a);
  #pragma unroll
  for (int s=32;s>=1;s>>=1) a += __shfl_xor(a, s, 64);
  if (ln == 0) b7[o] = a;
}

__global__ __launch_bounds__(256) void w9_kernel(
    const float* __restrict__ W9, const float* __restrict__ h8, float* __restrict__ out, int N)
{
  int n = blockIdx.x*256 + threadIdx.x;
  if (n >= N) return;
  float a0=0.f, a1=0.f, a2=0.f;
  for (int c=0;c<256;++c){
    float xv = h8[(size_t)c*N + n];
    a0 = fmaf(W9[c],       xv, a0);
    a1 = fmaf(W9[256+c],   xv, a1);
    a2 = fmaf(W9[512+c],   xv, a2);
  }
  out[(size_t)n*3+0]=a0; out[(size_t)n*3+1]=a1; out[(size_t)n*3+2]=a2;
}

extern "C" void kernel_launch(void* const* d_in, const int* in_sizes, int n_in,
                              void* d_out, int out_size, void* d_ws, size_t ws_size,
                              hipStream_t stream) {
  const float* curr_pos = (const float*)d_in[0];
  const int*   node_t   = (const int*)  d_in[1];
  const float* W1 = (const float*)d_in[2];
  const float* W2 = (const float*)d_in[3];
  const float* W3 = (const float*)d_in[4];
  const float* W4 = (const float*)d_in[5];
  const float* W5 = (const float*)d_in[6];
  const float* W6 = (const float*)d_in[7];
  const float* W7 = (const float*)d_in[8];
  const float* W8 = (const float*)d_in[9];
  const float* W9 = (const float*)d_in[10];
  const float* bn1 = (const float*)d_in[11];
  const float* bn2 = (const float*)d_in[12];
  const float* bn3 = (const float*)d_in[13];
  const float* bn4 = (const float*)d_in[14];
  const float* bn5 = (const float*)d_in[15];
  const float* bn6 = (const float*)d_in[16];
  const float* bn7 = (const float*)d_in[17];
  const float* bn8 = (const float*)d_in[18];
  float* out = (float*)d_out;

  const int N = in_sizes[0] / 3;

  char* ws = (char*)d_ws;
  size_t off = 0;
  auto A = [&](size_t b){ size_t o = off; off = (o + b + 255) & ~(size_t)255; return o; };

  float* x0CN = (float*)(ws + A((size_t)N*12*4));
  unsigned short* xh0 = (unsigned short*)(ws + A((size_t)N*32*2));
  unsigned short* xx0 = (unsigned short*)(ws + A((size_t)N*2));
  float* x1CN = (float*)(ws + A((size_t)N*64*4));
  unsigned short* xh1 = (unsigned short*)(ws + A((size_t)N*64*2));
  unsigned short* xx1 = (unsigned short*)(ws + A((size_t)N*2));
  float* x2CN = (float*)(ws + A((size_t)N*64*4));
  unsigned short* xh2 = (unsigned short*)(ws + A((size_t)N*64*2));
  unsigned short* xx2 = (unsigned short*)(ws + A((size_t)N*2));
  float* x3CN = (float*)(ws + A((size_t)N*64*4));
  int* idxb = (int*)(ws + A((size_t)N*KNN_K*4));
  unsigned* pl = (unsigned*)(ws + A((size_t)2*N*KNN_K*4));
  float* Ut  = (float*)(ws + A((size_t)N*64*4));
  float* Vtb = (float*)(ws + A((size_t)N*64*4));
  float* w6t  = (float*)(ws + A((size_t)192*1024*4));
  float* w7xt = (float*)(ws + A((size_t)192*512*4));
  float* w8t  = (float*)(ws + A((size_t)512*256*4));
  float* gpart= (float*)(ws + A((size_t)1024*(N/64)*4));
  float* gbuf = (float*)(ws + A((size_t)1024*4));
  float* b7   = (float*)(ws + A((size_t)512*4));

  size_t h7B   = (size_t)512*N*4;
  size_t h8B   = (size_t)256*N*4;
  size_t uniOff = A(((h7B + 255) & ~(size_t)255) + h8B);
  float* h7   = (float*)(ws + uniOff);
  float* h8   = (float*)(ws + uniOff + ((h7B + 255) & ~(size_t)255));
  if (off > ws_size) return;

  dim3 b256(256), b512(512);
  build_x0<<<dim3((N+255)/256), b256, 0, stream>>>(curr_pos, node_t, x0CN, xh0, xx0, N);
  transpose_w<<<dim3((1024*192+255)/256), b256, 0, stream>>>(W6, w6t, 1024, 192, 192, 0);
  transpose_w<<<dim3((512*192+255)/256),  b256, 0, stream>>>(W7, w7xt, 512, 192, 1216, 1024);
  transpose_w<<<dim3((256*512+255)/256),  b256, 0, stream>>>(W8, w8t, 256, 512, 512, 0);

  dim3 gknn(N/16, 2);
  dim3 guv(N/256, 2, 2);
  dim3 gec(N/8);
  dim3 gfin((N+255)/256);

  // round 1
  knn_mfma<32><<<gknn, b512, 0, stream>>>(xh0, xx0, pl, N);
  knn_final<<<gfin, b256, 0, stream>>>(pl, idxb, N);
  uv_kernel<12><<<guv, b256, 0, stream>>>(x0CN, W1, bn1, Ut, Vtb, N);
  edge2<true><<<gec, b256, 0, stream>>>(Ut, Vtb, idxb, W2, bn2, x1CN, xh1, xx1, N);
  // round 2
  knn_mfma<64><<<gknn, b512, 0, stream>>>(xh1, xx1, pl, N);
  knn_final<<<gfin, b256, 0, stream>>>(pl, idxb, N);
  uv_kernel<64><<<guv, b256, 0, stream>>>(x1CN, W3, bn3, Ut, Vtb, N);
  edge2<true><<<gec, b256, 0, stream>>>(Ut, Vtb, idxb, W4, bn4, x2CN, xh2, xx2, N);
  // round 3
  knn_mfma<64><<<gknn, b512, 0, stream>>>(xh2, xx2, pl, N);
  knn_final<<<gfin, b256, 0, stream>>>(pl, idxb, N);
  uv_kernel<64><<<guv, b256, 0, stream>>>(x2CN, W5, bn5, Ut, Vtb, N);
  edge2<false><<<gec, b256, 0, stream>>>(Ut, Vtb, idxb, nullptr, nullptr, x3CN, nullptr, nullptr, N);
  // head
  conv_fused<true><<<dim3(N/128, 16), b256, 0, stream>>>(w6t, 1024, x1CN, 64, x2CN, 64, x3CN, 64, bn6, nullptr, gpart, N);
  gmax_final<<<dim3(4), b256, 0, stream>>>(gpart, gbuf, 1024, N/128);
  bias7_kernel<<<dim3(128), b256, 0, stream>>>(W7, gbuf, b7);
  conv_fused<false><<<dim3(N/128, 8), b256, 0, stream>>>(w7xt, 512, x1CN, 64, x2CN, 64, x3CN, 64, bn7, b7, h7, N);
  conv_fused<false><<<dim3(N/128, 4), b256, 0, stream>>>(w8t, 256, h7, 512, nullptr, 0, nullptr, 0, bn8, nullptr, h8, N);
  w9_kernel<<<gfin, b256, 0, stream>>>(W9, h8, out, N);
}